// Round 10
// baseline (106.328 us; speedup 1.0000x reference)
//
#include <hip/hip_runtime.h>
#include <stdint.h>

// PETNNCell collapse (proven analytically):
//   T_t == 0, m == 1;  C_new = I_t + Z_c;  h = sigmoid(X @ W_h[:, :512]^T + b_h)
//   S_new = sigmoid((1 - Z_w)*S_prev + Z_w*h + X)
//
// R10: the R5-R9 plateau (~25% MfmaUtil across 4 schedules) was the unified-
// register wall: 124 VGPR + 128 acc AGPR = 252/256 at 2 waves/SIMD -> the
// compiler could not software-pipeline LDS reads, and 2 lockstep waves/SIMD
// cannot hide each other's lgkm stalls. Fix: 1024-thread blocks, 16 waves
// (4M x 4N), wave tile 64x32/output -> acc 64, frags 8/kk, ~100 VGPR total
// -> 4 waves/SIMD. Stalls now overlap across waves (TLP, not ILP).
// Same BM=256 x BN=128 fam-split geometry, R9's 1-barrier-per-tile loop.

#define BROWS 16384
#define DDIM  512

typedef __bf16 bf16x8 __attribute__((ext_vector_type(8)));
typedef __bf16 bf16x4 __attribute__((ext_vector_type(4)));
typedef float  f32x4  __attribute__((ext_vector_type(4)));

__device__ __forceinline__ float sigf(float x) { return 1.0f / (1.0f + __expf(-x)); }

__device__ __forceinline__ bf16x4 cvt4(f32x4 v) {
    bf16x4 r;
    r[0] = (__bf16)v[0]; r[1] = (__bf16)v[1];
    r[2] = (__bf16)v[2]; r[3] = (__bf16)v[3];
    return r;
}

__device__ __forceinline__ void glds16(const __bf16* g, __bf16* l) {
    __builtin_amdgcn_global_load_lds(
        (const __attribute__((address_space(1))) void*)g,
        (__attribute__((address_space(3))) void*)l, 16, 0, 0);
}

#define BAR   __builtin_amdgcn_s_barrier()
#define SB0   __builtin_amdgcn_sched_barrier(0)
#define VM0   asm volatile("s_waitcnt vmcnt(0)" ::: "memory")
#define MEMF  asm volatile("" ::: "memory")

// ===================== prepass: X, S, weights -> bf16 =====================
// ws elems: [0) Xb 8388608 | [8388608) Sb 8388608 | [16777216) weights:
//   +0 Wzw 512x1024 | +524288 Wh' 512x512 | +786432 Wzc 512x1024 | +1310720 Wit 512x512
__global__ __launch_bounds__(256)
void petnn_cvt(const float* __restrict__ X,   const float* __restrict__ S,
               const float* __restrict__ Wzw, const float* __restrict__ Wh,
               const float* __restrict__ Wzc, const float* __restrict__ Wit,
               __bf16* __restrict__ ws)
{
    const int i = blockIdx.x * 256 + threadIdx.x;   // f32x4 chunk, 4587520 total
    const float* src; size_t dst;
    if (i < 2097152)      { src = X + (size_t)i * 4; dst = (size_t)i * 4; }
    else if (i < 4194304) { const int j = i - 2097152;
                            src = S + (size_t)j * 4; dst = 8388608 + (size_t)j * 4; }
    else {
        const int j = i - 4194304;                  // 0..393215 (weights)
        if (j < 131072)      { src = Wzw + (size_t)j * 4;
                               dst = 16777216 + (size_t)j * 4; }
        else if (j < 196608) { const int jj = j - 131072;   // Wh cols 0..511
                               src = Wh + (size_t)(jj >> 7) * 1024 + (jj & 127) * 4;
                               dst = 16777216 + 524288 + (size_t)jj * 4; }
        else if (j < 327680) { const int jj = j - 196608;
                               src = Wzc + (size_t)jj * 4;
                               dst = 16777216 + 786432 + (size_t)jj * 4; }
        else                 { const int jj = j - 327680;
                               src = Wit + (size_t)jj * 4;
                               dst = 16777216 + 1310720 + (size_t)jj * 4; }
    }
    *(bf16x4*)(ws + dst) = cvt4(*(const f32x4*)src);
}

// ===================== main: 16-wave, 4 waves/SIMD fused GEMM =====================
// BM=256 x BN=128, 2 outputs (P,Q), BK=64, 16 K-tiles (Q only kt<8).
// 1024 thr = 16 waves 4(M) x 4(N); wave tile 64x32 per output; acc 64/thread.
// LDS: sA dbuf 2x32K + sB dbuf 2x(P16K+Q16K) = 128 KiB, 1 block/CU.
__global__ __launch_bounds__(1024, 4)
void petnn_fused7(const __bf16* __restrict__ Xb, const __bf16* __restrict__ Sb,
                  const __bf16* __restrict__ wb,
                  const float* __restrict__ bzw, const float* __restrict__ bh,
                  const float* __restrict__ bzc, const float* __restrict__ bit_,
                  float* __restrict__ out)
{
    __shared__ __align__(16) __bf16 sA[2 * 256 * 64];       // 64 KiB [par][256r][64k]
    __shared__ __align__(16) __bf16 sB[2 * 2 * 128 * 64];   // 64 KiB [par][P/Q][128c][64k]

    const int tid = threadIdx.x;
    const int bid = blockIdx.x;
    // XCD-chunked swizzle (512 wgs, bijective; HW XCD = bid & 7): per XCD
    // 8 consecutive mblk x (4 nblk x 2 fam) -> A panel shared 8x in L2.
    const int orig = (bid & 7) * 64 + (bid >> 3);
    const int fam  = orig & 1;
    const int nblk = (orig >> 1) & 3;
    const int mblk = orig >> 3;            // 0..63

    const int lane = tid & 63, wid = tid >> 6;
    const int wm = wid >> 2;               // 0..3 (64-row slice of 256)
    const int wn = wid & 3;                // 0..3 (32-col slice of 128)
    const int l15 = lane & 15;
    const int kq  = (lane >> 4) * 8;

    const int arow0 = mblk * 256;
    const int ncol0 = nblk * 128;

    // staging (XOR swizzle baked into GLOBAL addr; LDS dest linear):
    // thread t stages row/col (t>>3) of a 128-row group, chunk (t&7).
    const int gr   = tid >> 3;             // 0..127
    const int gswz = ((tid & 7) ^ (gr & 7)) << 3;
    const __bf16* pXA = Xb + (size_t)(arow0 + gr) * 512 + gswz;
    const __bf16* pSA = Sb + (size_t)(arow0 + gr) * 512 + gswz;
    const __bf16* wbase = wb + (size_t)fam * 786432;
    const __bf16* pP = wbase + (size_t)(ncol0 + gr) * 1024 + gswz;           // K=1024
    const __bf16* pQ = wbase + 524288 + (size_t)(ncol0 + gr) * 512 + gswz;   // K=512

    // fragment read offsets (elem, within 16384-elem A slot / 8192-elem B half)
    int aoff[2][4], boff[2][2];
    #pragma unroll
    for (int f = 0; f < 4; ++f) {
        const int r = wm * 64 + f * 16 + l15;
        aoff[0][f] = r * 64 + (kq        ^ ((r & 7) * 8));
        aoff[1][f] = r * 64 + ((32 + kq) ^ ((r & 7) * 8));
    }
    #pragma unroll
    for (int f = 0; f < 2; ++f) {
        const int c = wn * 32 + f * 16 + l15;
        boff[0][f] = c * 64 + (kq        ^ ((c & 7) * 8));
        boff[1][f] = c * 64 + ((32 + kq) ^ ((c & 7) * 8));
    }

    f32x4 accP[4][2] = {}, accQ[4][2] = {};

    // one glds per unit: 1024 thr x 16B = 16 KiB
#define ISSUE_A(T) { \
        const __bf16* ab_ = ((T) < 8) ? pXA : pSA; \
        const int kga_ = ((T) & 7) * 64; \
        __bf16* d_ = sA + ((T) & 1) * 16384 + tid * 8; \
        glds16(ab_ + kga_, d_); \
        glds16(ab_ + 65536 + kga_, d_ + 8192); }
#define ISSUE_P(T) { \
        glds16(pP + (T) * 64, sB + ((T) & 1) * 16384 + tid * 8); }
#define ISSUE_Q(T) { \
        glds16(pQ + (T) * 64, sB + ((T) & 1) * 16384 + 8192 + tid * 8); }

    // one kk half: 8 frag reads + 16/8 MFMA; no manual fences inside —
    // 4 waves/SIMD hide the lgkm latency across waves.
#define KK_FULL(KK) { \
        bf16x8 af[4], bp[2], bq[2]; \
        _Pragma("unroll") \
        for (int f = 0; f < 4; ++f) af[f] = *(const bf16x8*)(aS_ + aoff[KK][f]); \
        _Pragma("unroll") \
        for (int f = 0; f < 2; ++f) bp[f] = *(const bf16x8*)(bS_ + boff[KK][f]); \
        _Pragma("unroll") \
        for (int f = 0; f < 2; ++f) bq[f] = *(const bf16x8*)(bS_ + 8192 + boff[KK][f]); \
        __builtin_amdgcn_s_setprio(1); \
        _Pragma("unroll") \
        for (int nf = 0; nf < 2; ++nf) \
            _Pragma("unroll") \
            for (int mf = 0; mf < 4; ++mf) \
                accP[mf][nf] = __builtin_amdgcn_mfma_f32_16x16x32_bf16(af[mf], bp[nf], accP[mf][nf], 0, 0, 0); \
        _Pragma("unroll") \
        for (int nf = 0; nf < 2; ++nf) \
            _Pragma("unroll") \
            for (int mf = 0; mf < 4; ++mf) \
                accQ[mf][nf] = __builtin_amdgcn_mfma_f32_16x16x32_bf16(af[mf], bq[nf], accQ[mf][nf], 0, 0, 0); \
        __builtin_amdgcn_s_setprio(0); }

#define KK_TAIL(KK) { \
        bf16x8 af[4], bp[2]; \
        _Pragma("unroll") \
        for (int f = 0; f < 4; ++f) af[f] = *(const bf16x8*)(aS_ + aoff[KK][f]); \
        _Pragma("unroll") \
        for (int f = 0; f < 2; ++f) bp[f] = *(const bf16x8*)(bS_ + boff[KK][f]); \
        __builtin_amdgcn_s_setprio(1); \
        _Pragma("unroll") \
        for (int nf = 0; nf < 2; ++nf) \
            _Pragma("unroll") \
            for (int mf = 0; mf < 4; ++mf) \
                accP[mf][nf] = __builtin_amdgcn_mfma_f32_16x16x32_bf16(af[mf], bp[nf], accP[mf][nf], 0, 0, 0); \
        __builtin_amdgcn_s_setprio(0); }

    // STEP(T): vmcnt(0) is not a stall — tile T's glds were issued one full
    // tile body earlier. Single barrier publishes tile T's LDS and certifies
    // buf[(T+1)&1] free (T-1 readers drained via MFMA operand waits).
#define STEP(T) { \
        VM0; SB0; BAR; \
        if ((T) + 1 < 16) { \
            ISSUE_A((T) + 1) ISSUE_P((T) + 1) \
            if ((T) + 1 < 8) ISSUE_Q((T) + 1) \
        } \
        MEMF; \
        const __bf16* aS_ = sA + ((T) & 1) * 16384; \
        const __bf16* bS_ = sB + ((T) & 1) * 16384; \
        if ((T) < 8) { KK_FULL(0) KK_FULL(1) } \
        else         { KK_TAIL(0) KK_TAIL(1) } }

    // prologue: tile 0's units only
    ISSUE_A(0) ISSUE_P(0) ISSUE_Q(0)

    STEP(0)  STEP(1)  STEP(2)  STEP(3)
    STEP(4)  STEP(5)  STEP(6)  STEP(7)
    STEP(8)  STEP(9)  STEP(10) STEP(11)
    STEP(12) STEP(13) STEP(14) STEP(15)

#undef STEP
#undef KK_FULL
#undef KK_TAIL
#undef ISSUE_A
#undef ISSUE_P
#undef ISSUE_Q

    // ---- fused epilogue ----
    // C/D frag layout (m89/m91): col = lane&15, row = (lane>>4)*4 + reg
    const int rowb = arow0 + wm * 64;
    const int colb = ncol0 + wn * 32;
    if (fam == 0) {
        #pragma unroll
        for (int nf = 0; nf < 2; ++nf) {
            const int col = colb + nf * 16 + l15;
            const float vzw = bzw[col], vh = bh[col];
            #pragma unroll
            for (int mf = 0; mf < 4; ++mf) {
                #pragma unroll
                for (int j = 0; j < 4; ++j) {
                    const int row = rowb + mf * 16 + ((lane >> 4) << 2) + j;
                    const size_t off = (size_t)row * DDIM + col;
                    const float zw = sigf(accP[mf][nf][j] + vzw);
                    const float hh = sigf(accQ[mf][nf][j] + vh);
                    out[off] = sigf((1.0f - zw) * (float)Sb[off] + zw * hh
                                    + (float)Xb[off]);                 // S_new
                }
            }
        }
    } else {
        #pragma unroll
        for (int nf = 0; nf < 2; ++nf) {
            const int col = colb + nf * 16 + l15;
            const float vzc = bzc[col], vit = bit_[col];
            #pragma unroll
            for (int mf = 0; mf < 4; ++mf) {
                #pragma unroll
                for (int j = 0; j < 4; ++j) {
                    const int row = rowb + mf * 16 + ((lane >> 4) << 2) + j;
                    const size_t off = (size_t)row * DDIM + col;
                    out[(size_t)BROWS * DDIM + off] =
                        (accP[mf][nf][j] + vzc) + (accQ[mf][nf][j] + vit); // C_new
                }
            }
        }
    }
}

// ===================== fallback (ws too small): R4 path =====================
__global__ __launch_bounds__(256)
void petnn_cvtw(const float* __restrict__ Wzw, const float* __restrict__ Wh,
                const float* __restrict__ Wzc, const float* __restrict__ Wit,
                __bf16* __restrict__ wb)
{
    const int i = blockIdx.x * 256 + threadIdx.x;
    const float* src; size_t dst;
    if (i < 131072)      { src = Wzw + (size_t)i * 4;  dst = (size_t)i * 4; }
    else if (i < 196608) { const int j = i - 131072;
                           src = Wh + (size_t)(j >> 7) * 1024 + (j & 127) * 4;
                           dst = 524288 + (size_t)j * 4; }
    else if (i < 327680) { const int j = i - 196608;
                           src = Wzc + (size_t)j * 4;  dst = 786432 + (size_t)j * 4; }
    else                 { const int j = i - 327680;
                           src = Wit + (size_t)j * 4;  dst = 1310720 + (size_t)j * 4; }
    *(bf16x4*)(wb + dst) = cvt4(*(const f32x4*)src);
}

__global__ __launch_bounds__(512, 4)
void petnn_fused(const float* __restrict__ X,   const float* __restrict__ S,
                 const __bf16* __restrict__ wb,
                 const float* __restrict__ bzw, const float* __restrict__ bh,
                 const float* __restrict__ bzc, const float* __restrict__ bit_,
                 float* __restrict__ out)
{
    __shared__ __align__(16) __bf16 sA[128 * 64];
    __shared__ __align__(16) __bf16 sB[2 * 2 * 64 * 64];

    const int tid = threadIdx.x;
    const int bid = blockIdx.x;
    const int orig = (bid & 7) * 256 + (bid >> 3);
    const int fam  = orig & 1;
    const int nblk = (orig >> 1) & 7;
    const int mblk = orig >> 4;
    const int lane = tid & 63, wid = tid >> 6;
    const int wm = wid >> 2, wn = wid & 3;
    const int arow0 = mblk * 128, ncol0 = nblk * 64;
    const int srow = tid >> 4, skq = (tid & 15) << 2;
    const int bn = tid >> 3;
    const int bks = ((tid & 7) ^ (bn & 7)) << 3;
    const __bf16* wP = wb + (size_t)fam * 786432 + (size_t)(ncol0 + bn) * 1024 + bks;
    const __bf16* wQ = wb + (size_t)fam * 786432 + 524288 + (size_t)(ncol0 + bn) * 512 + bks;
    __bf16* ldsB = sB + tid * 8;

    f32x4 aP[4] = {}, aQ[4] = {};
    f32x4 ra[4];

    glds16(wP, ldsB);
    glds16(wQ, ldsB + 4096);
    #pragma unroll
    for (int p = 0; p < 4; ++p)
        ra[p] = *(const f32x4*)(X + (size_t)(arow0 + p * 32 + srow) * DDIM + skq);
    glds16(wP + 64, ldsB + 8192);
    glds16(wQ + 64, ldsB + 8192 + 4096);

    for (int kt = 0; kt < 16; ++kt) {
        const bool full = kt < 8;
        #pragma unroll
        for (int p = 0; p < 4; ++p) {
            const int r = p * 32 + srow;
            *(bf16x4*)(sA + r * 64 + (skq ^ ((r & 7) * 8))) = cvt4(ra[p]);
        }
        if (kt + 1 < 16) {
            const float* asrc = (kt + 1 < 8) ? X : S;
            const int kga = ((kt + 1) & 7) * 64 + skq;
            #pragma unroll
            for (int p = 0; p < 4; ++p)
                ra[p] = *(const f32x4*)(asrc + (size_t)(arow0 + p * 32 + srow) * DDIM + kga);
        }
        asm volatile("s_waitcnt lgkmcnt(0)" ::: "memory");
        __builtin_amdgcn_s_barrier();

        const __bf16* bb = sB + (kt & 1) * 8192;
        #pragma unroll
        for (int kk = 0; kk < 2; ++kk) {
            const int kbe = kk * 32 + (lane >> 4) * 8;
            bf16x8 af[4];
            #pragma unroll
            for (int mf = 0; mf < 4; ++mf) {
                const int r = wm * 64 + mf * 16 + (lane & 15);
                af[mf] = *(const bf16x8*)(sA + r * 64 + (kbe ^ ((r & 7) * 8)));
            }
            const int nr = wn * 16 + (lane & 15);
            const int sx = nr * 64 + (kbe ^ ((nr & 7) * 8));
            const bf16x8 bP = *(const bf16x8*)(bb + sx);
            #pragma unroll
            for (int mf = 0; mf < 4; ++mf)
                aP[mf] = __builtin_amdgcn_mfma_f32_16x16x32_bf16(af[mf], bP, aP[mf], 0, 0, 0);
            if (full) {
                const bf16x8 bQ = *(const bf16x8*)(bb + 4096 + sx);
                #pragma unroll
                for (int mf = 0; mf < 4; ++mf)
                    aQ[mf] = __builtin_amdgcn_mfma_f32_16x16x32_bf16(af[mf], bQ, aQ[mf], 0, 0, 0);
            }
        }

        if (kt + 1 < 16) {
            asm volatile("" ::: "memory");
            __builtin_amdgcn_s_barrier();
            asm volatile("" ::: "memory");
            if (kt + 2 < 16) {
                __bf16* bd = sB + (kt & 1) * 8192 + tid * 8;
                glds16(wP + (size_t)(kt + 2) * 64, bd);
                if (kt + 2 < 8) glds16(wQ + (size_t)(kt + 2) * 64, bd + 4096);
            }
        }
    }

    const int col  = ncol0 + wn * 16 + (lane & 15);
    const int rowb = arow0 + wm * 64;
    if (fam == 0) {
        const float vzw = bzw[col], vh = bh[col];
        #pragma unroll
        for (int mf = 0; mf < 4; ++mf) {
            #pragma unroll
            for (int j = 0; j < 4; ++j) {
                const int row = rowb + mf * 16 + ((lane >> 4) << 2) + j;
                const size_t off = (size_t)row * DDIM + col;
                const float zw = sigf(aP[mf][j] + vzw);
                const float hh = sigf(aQ[mf][j] + vh);
                out[off] = sigf((1.0f - zw) * S[off] + zw * hh + X[off]);
            }
        }
    } else {
        const float vzc = bzc[col], vit = bit_[col];
        #pragma unroll
        for (int mf = 0; mf < 4; ++mf) {
            #pragma unroll
            for (int j = 0; j < 4; ++j) {
                const int row = rowb + mf * 16 + ((lane >> 4) << 2) + j;
                const size_t off = (size_t)row * DDIM + col;
                out[(size_t)BROWS * DDIM + off] =
                    (aP[mf][j] + vzc) + (aQ[mf][j] + vit);
            }
        }
    }
}

__global__ void petnn_zeroT(float* __restrict__ t) {
    t[blockIdx.x * 256 + threadIdx.x] = 0.0f;   // T_t == 0 exactly
}

extern "C" void kernel_launch(void* const* d_in, const int* in_sizes, int n_in,
                              void* d_out, int out_size, void* d_ws, size_t ws_size,
                              hipStream_t stream) {
    (void)in_sizes; (void)n_in; (void)out_size;
    const float* X    = (const float*)d_in[0];
    const float* S    = (const float*)d_in[1];
    const float* Wzc  = (const float*)d_in[6];
    const float* bzc  = (const float*)d_in[7];
    const float* Wzw  = (const float*)d_in[8];
    const float* bzw  = (const float*)d_in[9];
    const float* Wit  = (const float*)d_in[10];
    const float* bit_ = (const float*)d_in[11];
    const float* Wh   = (const float*)d_in[14];
    const float* bh   = (const float*)d_in[15];
    float* out = (float*)d_out;

    if (ws_size >= 36700160u) {
        __bf16* ws = (__bf16*)d_ws;
        const __bf16* Xb = ws;
        const __bf16* Sb = ws + 8388608;
        const __bf16* wb = ws + 16777216;
        petnn_cvt<<<dim3(17920), dim3(256), 0, stream>>>(X, S, Wzw, Wh, Wzc, Wit, ws);
        petnn_fused7<<<dim3(512), dim3(1024), 0, stream>>>(
            Xb, Sb, wb, bzw, bh, bzc, bit_, out);
    } else {
        __bf16* wb = (__bf16*)d_ws;
        petnn_cvtw<<<dim3(1536), dim3(256), 0, stream>>>(Wzw, Wh, Wzc, Wit, wb);
        petnn_fused<<<dim3(2048), dim3(512), 0, stream>>>(
            X, S, wb, bzw, bh, bzc, bit_, out);
    }
    petnn_zeroT<<<dim3(64), dim3(256), 0, stream>>>(out + 2 * (size_t)BROWS * DDIM);
}